// Round 2
// baseline (841.910 us; speedup 1.0000x reference)
//
#include <hip/hip_runtime.h>
#include <hip/hip_bf16.h>

typedef __bf16 bf16;
typedef __bf16 bf16x8 __attribute__((ext_vector_type(8)));
typedef float f32x4 __attribute__((ext_vector_type(4)));

#define LL 1024
#define SS 1024
#define BB 4
#define EE 1024
#define HH 16
#define MM 256
#define HD 64
#define BH 64

__device__ __forceinline__ f32x4 mfma16(bf16x8 a, bf16x8 b, f32x4 c) {
  return __builtin_amdgcn_mfma_f32_16x16x32_bf16(a, b, c, 0, 0, 0);
}

// load 8 contiguous f32 (32B-aligned) -> bf16x8 fragment
__device__ __forceinline__ bf16x8 cvt8(const float* p) {
  const f32x4 lo = *reinterpret_cast<const f32x4*>(p);
  const f32x4 hi = *reinterpret_cast<const f32x4*>(p + 4);
  bf16x8 r;
  r[0] = (bf16)lo[0]; r[1] = (bf16)lo[1]; r[2] = (bf16)lo[2]; r[3] = (bf16)lo[3];
  r[4] = (bf16)hi[0]; r[5] = (bf16)hi[1]; r[6] = (bf16)hi[2]; r[7] = (bf16)hi[3];
  return r;
}

// ---------------------------------------------------------------------------
// Projection GEMM: out = X(4096xE) @ W^T + bias, with per-mode epilogue.
// MODE 0: q (f32 in) -> *0.125, rotary(q_pe),  write qh  (BH, L, HD) bf16
// MODE 1: k (f32 in) -> rotary(kv_pe),         write kh  (BH, S, HD) bf16
// MODE 2: v (f32 in) ->                        write vhT (BH, HD, S) bf16
// MODE 3: out-proj (bf16 attn2 in, f32 W) ->   write (L*B, E) f32 (= d_out)
// ---------------------------------------------------------------------------
template <int MODE>
__global__ __launch_bounds__(256) void proj_kernel(
    const float* __restrict__ Xf, const bf16* __restrict__ Xb,
    const float* __restrict__ W, const float* __restrict__ bias,
    const float* __restrict__ pe, bf16* __restrict__ outb,
    float* __restrict__ outf) {
  const int tid = threadIdx.x;
  const int wv = tid >> 6, lane = tid & 63;
  const int lrow = lane & 15, lkg = lane >> 4;
  const int r0 = blockIdx.x * 64 + wv * 16;
  const int c0 = blockIdx.y * 64;

  const float* Af = (MODE == 3) ? nullptr : Xf + (size_t)(r0 + lrow) * EE + lkg * 8;
  const bf16* Ab = (MODE == 3) ? Xb + (size_t)(r0 + lrow) * EE + lkg * 8 : nullptr;
  const float* Bp = W + (size_t)(c0 + lrow) * EE + lkg * 8;

  const f32x4 zero = {0.f, 0.f, 0.f, 0.f};
  f32x4 acc[4];
#pragma unroll
  for (int i = 0; i < 4; ++i) acc[i] = zero;

  for (int k0 = 0; k0 < EE; k0 += 32) {
    bf16x8 a;
    if (MODE == 3) a = *reinterpret_cast<const bf16x8*>(Ab + k0);
    else           a = cvt8(Af + k0);
#pragma unroll
    for (int ct = 0; ct < 4; ++ct) {
      bf16x8 b = cvt8(Bp + (size_t)ct * 16 * EE + k0);
      acc[ct] = mfma16(a, b, acc[ct]);
    }
  }

#pragma unroll
  for (int ct = 0; ct < 4; ++ct) {
    const int col = c0 + ct * 16 + lrow;
    const float bs = bias[col];
#pragma unroll
    for (int r = 0; r < 4; ++r) {
      const int rowg = r0 + lkg * 4 + r;
      const int t = rowg >> 2;   // l or s index (rows are t*B + b)
      const int b = rowg & 3;
      float v = acc[ct][r] + bs;
      if (MODE == 0) v *= 0.125f;  // HD^-0.5
      if (MODE <= 1) {
        // interleaved rotary: x2[2i]=-x[2i+1], x2[2i+1]=x[2i]; out=x*cos+x2*sin
        const float* pc = pe + (((size_t)b * LL + t) * EE + col) * 2;
        const float cs = pc[0], sn = pc[1];
        const float vp = __shfl_xor(v, 1);            // partner col^1 (lane^1)
        const float x2 = (col & 1) ? vp : -vp;
        v = v * cs + x2 * sn;
      }
      if (MODE == 3) {
        outf[(size_t)rowg * EE + col] = v;
      } else {
        const int h = col >> 6, d = col & 63;
        const int bh = b * HH + h;
        if (MODE == 2)
          outb[((size_t)bh * HD + d) * SS + t] = (bf16)v;   // vhT[bh][d][s]
        else
          outb[((size_t)bh * LL + t) * HD + d] = (bf16)v;   // qh/kh[bh][t][d]
      }
    }
  }
}

// ---------------------------------------------------------------------------
// Column softmax stats over L for each (bh, s): m_s = max_l score, dinv = 1/sum
// ---------------------------------------------------------------------------
__global__ __launch_bounds__(256) void stats_kernel(
    const bf16* __restrict__ qh, const bf16* __restrict__ kh,
    float* __restrict__ ms, float* __restrict__ dinv) {
  const int tid = threadIdx.x;
  const int wv = tid >> 6, lane = tid & 63;
  const int lrow = lane & 15, lkg = lane >> 4;
  const int bh = blockIdx.x;
  const int s0 = blockIdx.y * 64 + wv * 16;

  const bf16* kp = kh + ((size_t)bh * SS + s0 + lrow) * HD + lkg * 8;
  const bf16x8 b0 = *reinterpret_cast<const bf16x8*>(kp);
  const bf16x8 b1 = *reinterpret_cast<const bf16x8*>(kp + 32);

  const f32x4 zero = {0.f, 0.f, 0.f, 0.f};
  float m = -1e30f, d = 0.f;
  const bf16* qbase = qh + ((size_t)bh * LL + lrow) * HD + lkg * 8;
  for (int l0 = 0; l0 < LL; l0 += 16) {
    bf16x8 a0 = *reinterpret_cast<const bf16x8*>(qbase + (size_t)l0 * HD);
    bf16x8 a1 = *reinterpret_cast<const bf16x8*>(qbase + (size_t)l0 * HD + 32);
    f32x4 c = zero;
    c = mfma16(a0, b0, c);
    c = mfma16(a1, b1, c);
    float tm = fmaxf(fmaxf(c[0], c[1]), fmaxf(c[2], c[3]));
    float nm = fmaxf(m, tm);
    d = d * __expf(m - nm);
#pragma unroll
    for (int r = 0; r < 4; ++r) d += __expf(c[r] - nm);
    m = nm;
  }
  // combine the 4 row-groups (lanes l, l^16, l^32, l^48 share column s)
#pragma unroll
  for (int off = 16; off < 64; off <<= 1) {
    float mo = __shfl_xor(m, off);
    float dd = __shfl_xor(d, off);
    float nm = fmaxf(m, mo);
    d = d * __expf(m - nm) + dd * __expf(mo - nm);
    m = nm;
  }
  if (lane < 16) {
    ms[(size_t)bh * SS + s0 + lrow] = m;
    dinv[(size_t)bh * SS + s0 + lrow] = 1.f / d;
  }
}

// colsum_v[bh][d] = sum_s vhT[bh][d][s]   (for the +1e-8 correction)
__global__ __launch_bounds__(64) void colsum_kernel(
    const bf16* __restrict__ vhT, float* __restrict__ colsum) {
  const int bh = blockIdx.x, d = blockIdx.y, lane = threadIdx.x;
  const bf16* p = vhT + ((size_t)bh * HD + d) * SS;
  float s = 0.f;
  for (int i = lane; i < SS; i += 64) s += (float)p[i];
#pragma unroll
  for (int off = 32; off; off >>= 1) s += __shfl_xor(s, off);
  if (lane == 0) colsum[bh * HD + d] = s;
}

// vmT[bh][d][m] = v_mem[m][b][h*64+d]  (f32 -> bf16)
__global__ __launch_bounds__(256) void vmt_kernel(
    const float* __restrict__ v_mem, bf16* __restrict__ vmT) {
  const int bh = blockIdx.x;
  const int b = bh >> 4, h = bh & 15;
  const int tid = threadIdx.x;
  const int d = tid & 63;
  const int mo = tid >> 6;
  for (int m = mo; m < MM; m += 4) {
    float v = v_mem[((size_t)m * BB + b) * EE + h * 64 + d];
    vmT[((size_t)bh * HD + d) * MM + m] = (bf16)v;
  }
}

// ---------------------------------------------------------------------------
// Attention: main (col-softmax + row-renorm) + memory attention + gating.
// One wave = 16 query rows of one bh. Recomputes scores (cheap MFMA) instead
// of storing the SxL matrix.
// ---------------------------------------------------------------------------
__global__ __launch_bounds__(256) void attn_kernel(
    const bf16* __restrict__ qh, const bf16* __restrict__ kh,
    const bf16* __restrict__ vhT, const bf16* __restrict__ vmT,
    const float* __restrict__ k_mem, const float* __restrict__ gate_w,
    const float* __restrict__ ms, const float* __restrict__ dinv,
    const float* __restrict__ colsum, bf16* __restrict__ attn2) {
  __shared__ bf16 wt[4][16][40];  // per-wave P-tile, stride 40 (16B-aligned rows)
  const int tid = threadIdx.x;
  const int wv = tid >> 6, lane = tid & 63;
  const int lrow = lane & 15, lkg = lane >> 4;
  const int bh = blockIdx.x;
  const int b = bh >> 4, h = bh & 15;
  const int l0 = blockIdx.y * 64 + wv * 16;

  const bf16* qp = qh + ((size_t)bh * LL + l0 + lrow) * HD + lkg * 8;
  const bf16x8 aq0 = *reinterpret_cast<const bf16x8*>(qp);
  const bf16x8 aq1 = *reinterpret_cast<const bf16x8*>(qp + 32);

  const f32x4 zero = {0.f, 0.f, 0.f, 0.f};
  f32x4 acc[4], accm[4];
  float rsum[4] = {0.f, 0.f, 0.f, 0.f};
#pragma unroll
  for (int i = 0; i < 4; ++i) { acc[i] = zero; accm[i] = zero; }

  // ---- main attention ----
  for (int s0 = 0; s0 < SS; s0 += 32) {
    f32x4 sc[2];
#pragma unroll
    for (int t = 0; t < 2; ++t) {
      const bf16* kp = kh + ((size_t)bh * SS + s0 + t * 16 + lrow) * HD + lkg * 8;
      f32x4 c = zero;
      c = mfma16(aq0, *reinterpret_cast<const bf16x8*>(kp), c);
      c = mfma16(aq1, *reinterpret_cast<const bf16x8*>(kp + 32), c);
      sc[t] = c;
    }
#pragma unroll
    for (int t = 0; t < 2; ++t) {
      const int s = s0 + t * 16 + lrow;
      const float m_ = ms[(size_t)bh * SS + s];
      const float di = dinv[(size_t)bh * SS + s];
#pragma unroll
      for (int r = 0; r < 4; ++r) {
        float w = __expf(sc[t][r] - m_) * di;  // column-softmax value
        rsum[r] += w;
        wt[wv][lkg * 4 + r][t * 16 + lrow] = (bf16)w;
      }
    }
    __syncthreads();
    const bf16x8 aw = *reinterpret_cast<const bf16x8*>(&wt[wv][lrow][lkg * 8]);
#pragma unroll
    for (int dt = 0; dt < 4; ++dt) {
      const bf16* vp = vhT + ((size_t)bh * HD + dt * 16 + lrow) * SS + s0 + lkg * 8;
      acc[dt] = mfma16(aw, *reinterpret_cast<const bf16x8*>(vp), acc[dt]);
    }
    __syncthreads();
  }

  // ---- memory attention pass 1: per-row online stats ----
  float mx[4] = {-1e30f, -1e30f, -1e30f, -1e30f};
  float dn[4] = {0.f, 0.f, 0.f, 0.f};
  for (int m0 = 0; m0 < MM; m0 += 32) {
#pragma unroll
    for (int t = 0; t < 2; ++t) {
      const float* kp = k_mem + ((size_t)(m0 + t * 16 + lrow) * BB + b) * EE + h * 64 + lkg * 8;
      f32x4 c = zero;
      c = mfma16(aq0, cvt8(kp), c);
      c = mfma16(aq1, cvt8(kp + 32), c);
#pragma unroll
      for (int r = 0; r < 4; ++r) {
        float nm = fmaxf(mx[r], c[r]);
        dn[r] = dn[r] * __expf(mx[r] - nm) + __expf(c[r] - nm);
        mx[r] = nm;
      }
    }
  }
#pragma unroll
  for (int off = 1; off < 16; off <<= 1) {
#pragma unroll
    for (int r = 0; r < 4; ++r) {
      float mo = __shfl_xor(mx[r], off);
      float dd = __shfl_xor(dn[r], off);
      float nm = fmaxf(mx[r], mo);
      dn[r] = dn[r] * __expf(mx[r] - nm) + dd * __expf(mo - nm);
      mx[r] = nm;
    }
  }
#pragma unroll
  for (int r = 0; r < 4; ++r) dn[r] = 1.f / dn[r];

  // ---- memory attention pass 2: weights + PV ----
  for (int m0 = 0; m0 < MM; m0 += 32) {
#pragma unroll
    for (int t = 0; t < 2; ++t) {
      const float* kp = k_mem + ((size_t)(m0 + t * 16 + lrow) * BB + b) * EE + h * 64 + lkg * 8;
      f32x4 c = zero;
      c = mfma16(aq0, cvt8(kp), c);
      c = mfma16(aq1, cvt8(kp + 32), c);
#pragma unroll
      for (int r = 0; r < 4; ++r) {
        float w = __expf(c[r] - mx[r]) * dn[r];
        wt[wv][lkg * 4 + r][t * 16 + lrow] = (bf16)w;
      }
    }
    __syncthreads();
    const bf16x8 aw = *reinterpret_cast<const bf16x8*>(&wt[wv][lrow][lkg * 8]);
#pragma unroll
    for (int dt = 0; dt < 4; ++dt) {
      const bf16* vp = vmT + ((size_t)bh * HD + dt * 16 + lrow) * MM + m0 + lkg * 8;
      accm[dt] = mfma16(aw, *reinterpret_cast<const bf16x8*>(vp), accm[dt]);
    }
    __syncthreads();
  }

  // ---- epilogue: renormalize, gate, store ----
#pragma unroll
  for (int off = 1; off < 16; off <<= 1) {
#pragma unroll
    for (int r = 0; r < 4; ++r) rsum[r] += __shfl_xor(rsum[r], off);
  }
  float g = gate_w[h];
  g = 1.f / (1.f + __expf(-g));

#pragma unroll
  for (int dt = 0; dt < 4; ++dt) {
    const int d = dt * 16 + lrow;
    const float cv = colsum[bh * HD + d] * 1e-8f;
#pragma unroll
    for (int r = 0; r < 4; ++r) {
      const int lg = l0 + lkg * 4 + r;
      const float den = rsum[r] + (float)SS * 1e-8f;
      const float amain = (acc[dt][r] + cv) / den;
      const float v = g * accm[dt][r] + (1.f - g) * amain;
      attn2[((size_t)lg * BB + b) * EE + h * 64 + d] = (bf16)v;
    }
  }
}

// ---------------------------------------------------------------------------
extern "C" void kernel_launch(void* const* d_in, const int* in_sizes, int n_in,
                              void* d_out, int out_size, void* d_ws, size_t ws_size,
                              hipStream_t stream) {
  const float* query = (const float*)d_in[0];
  const float* key_i = (const float*)d_in[1];
  const float* value = (const float*)d_in[2];
  const float* ipw   = (const float*)d_in[3];
  const float* ipb   = (const float*)d_in[4];
  const float* opw   = (const float*)d_in[5];
  const float* opb   = (const float*)d_in[6];
  const float* q_pe  = (const float*)d_in[7];
  const float* kv_pe = (const float*)d_in[8];
  const float* k_mem = (const float*)d_in[9];
  const float* v_mem = (const float*)d_in[10];
  const float* gate  = (const float*)d_in[11];

  char* ws = (char*)d_ws;
  bf16* qh    = (bf16*)(ws);                  // 8 MB  (BH, L, HD)
  bf16* kh    = (bf16*)(ws + (8u << 20));     // 8 MB  (BH, S, HD)
  bf16* vhT   = (bf16*)(ws + (16u << 20));    // 8 MB  (BH, HD, S)
  bf16* attn2 = (bf16*)(ws + (24u << 20));    // 8 MB  (L*B, E)
  bf16* vmT   = (bf16*)(ws + (32u << 20));    // 2 MB  (BH, HD, M)
  float* ms     = (float*)(ws + (34u << 20));                 // 256 KB
  float* dinv   = (float*)(ws + (34u << 20) + (1u << 18));    // 256 KB
  float* colsum = (float*)(ws + (34u << 20) + (2u << 18));    // 16 KB

  dim3 blk(256);
  dim3 gP(64, 16);  // 4096 rows / 64, 1024 cols / 64
  hipLaunchKernelGGL((proj_kernel<0>), gP, blk, 0, stream, query, (const bf16*)nullptr, ipw, ipb, q_pe, qh, (float*)nullptr);
  hipLaunchKernelGGL((proj_kernel<1>), gP, blk, 0, stream, key_i, (const bf16*)nullptr, ipw + (size_t)EE * EE, ipb + EE, kv_pe, kh, (float*)nullptr);
  hipLaunchKernelGGL((proj_kernel<2>), gP, blk, 0, stream, value, (const bf16*)nullptr, ipw + 2 * (size_t)EE * EE, ipb + 2 * EE, (const float*)nullptr, vhT, (float*)nullptr);
  hipLaunchKernelGGL(stats_kernel, dim3(64, 16), blk, 0, stream, qh, kh, ms, dinv);
  hipLaunchKernelGGL(colsum_kernel, dim3(64, 64), dim3(64), 0, stream, vhT, colsum);
  hipLaunchKernelGGL(vmt_kernel, dim3(64), blk, 0, stream, v_mem, vmT);
  hipLaunchKernelGGL(attn_kernel, dim3(64, 16), blk, 0, stream, qh, kh, vhT, vmT, k_mem, gate, ms, dinv, colsum, attn2);
  hipLaunchKernelGGL((proj_kernel<3>), gP, blk, 0, stream, (const float*)nullptr, attn2, opw, opb, (const float*)nullptr, (bf16*)nullptr, (float*)d_out);
}

// Round 3
// 492.937 us; speedup vs baseline: 1.7079x; 1.7079x over previous
//
#include <hip/hip_runtime.h>
#include <hip/hip_bf16.h>

typedef __bf16 bf16;
typedef __bf16 bf16x8 __attribute__((ext_vector_type(8)));
typedef float f32x4 __attribute__((ext_vector_type(4)));

#define LL 1024
#define SS 1024
#define BB 4
#define EE 1024
#define HH 16
#define MM 256
#define HD 64
#define BH 64

__device__ __forceinline__ f32x4 mfma16(bf16x8 a, bf16x8 b, f32x4 c) {
  return __builtin_amdgcn_mfma_f32_16x16x32_bf16(a, b, c, 0, 0, 0);
}

// load 8 contiguous f32 (32B-aligned) -> bf16x8 fragment
__device__ __forceinline__ bf16x8 cvt8(const float* p) {
  const f32x4 lo = *reinterpret_cast<const f32x4*>(p);
  const f32x4 hi = *reinterpret_cast<const f32x4*>(p + 4);
  bf16x8 r;
  r[0] = (bf16)lo[0]; r[1] = (bf16)lo[1]; r[2] = (bf16)lo[2]; r[3] = (bf16)lo[3];
  r[4] = (bf16)hi[0]; r[5] = (bf16)hi[1]; r[6] = (bf16)hi[2]; r[7] = (bf16)hi[3];
  return r;
}

// f32 -> bf16 elementwise (8 elements/thread)
__global__ __launch_bounds__(256) void cvt_kernel(const float* __restrict__ in,
                                                  bf16* __restrict__ out, int n8) {
  int i = blockIdx.x * 256 + threadIdx.x;
  if (i < n8) {
    bf16x8 r = cvt8(in + (size_t)i * 8);
    *reinterpret_cast<bf16x8*>(out + (size_t)i * 8) = r;
  }
}

// ---------------------------------------------------------------------------
// Projection GEMM: out = X(4096xE) @ W^T + bias. W pre-converted to bf16.
// MODE 0: q (f32 in) -> *0.125, rotary(q_pe),  write qh  (BH, L, HD) bf16
// MODE 1: k (f32 in) -> rotary(kv_pe),         write kh  (BH, S, HD) bf16
// MODE 2: v (f32 in) ->                        write vhT (BH, HD, S) bf16
// MODE 3: out-proj (bf16 attn2 in) ->          write (L*B, E) f32 (= d_out)
// ---------------------------------------------------------------------------
template <int MODE>
__global__ __launch_bounds__(256) void proj_kernel(
    const float* __restrict__ Xf, const bf16* __restrict__ Xb,
    const bf16* __restrict__ W, const float* __restrict__ bias,
    const float* __restrict__ pe, bf16* __restrict__ outb,
    float* __restrict__ outf) {
  const int tid = threadIdx.x;
  const int wv = tid >> 6, lane = tid & 63;
  const int lrow = lane & 15, lkg = lane >> 4;
  const int r0 = blockIdx.x * 64 + wv * 16;
  const int c0 = blockIdx.y * 64;

  const float* Af = (MODE == 3) ? nullptr : Xf + (size_t)(r0 + lrow) * EE + lkg * 8;
  const bf16* Ab = (MODE == 3) ? Xb + (size_t)(r0 + lrow) * EE + lkg * 8 : nullptr;
  const bf16* Bp = W + (size_t)(c0 + lrow) * EE + lkg * 8;

  const f32x4 zero = {0.f, 0.f, 0.f, 0.f};
  f32x4 acc[4];
#pragma unroll
  for (int i = 0; i < 4; ++i) acc[i] = zero;

  for (int k0 = 0; k0 < EE; k0 += 32) {
    bf16x8 a;
    if (MODE == 3) a = *reinterpret_cast<const bf16x8*>(Ab + k0);
    else           a = cvt8(Af + k0);
#pragma unroll
    for (int ct = 0; ct < 4; ++ct) {
      bf16x8 b = *reinterpret_cast<const bf16x8*>(Bp + (size_t)ct * 16 * EE + k0);
      acc[ct] = mfma16(a, b, acc[ct]);
    }
  }

#pragma unroll
  for (int ct = 0; ct < 4; ++ct) {
    const int col = c0 + ct * 16 + lrow;
    const float bs = bias[col];
#pragma unroll
    for (int r = 0; r < 4; ++r) {
      const int rowg = r0 + lkg * 4 + r;
      const int t = rowg >> 2;   // l or s index (rows are t*B + b)
      const int b = rowg & 3;
      float v = acc[ct][r] + bs;
      if (MODE == 0) v *= 0.125f;  // HD^-0.5
      if (MODE <= 1) {
        // interleaved rotary: x2[2i]=-x[2i+1], x2[2i+1]=x[2i]; out=x*cos+x2*sin
        const float* pc = pe + (((size_t)b * LL + t) * EE + col) * 2;
        const float cs = pc[0], sn = pc[1];
        const float vp = __shfl_xor(v, 1);            // partner col^1 (lane^1)
        const float x2 = (col & 1) ? vp : -vp;
        v = v * cs + x2 * sn;
      }
      if (MODE == 3) {
        outf[(size_t)rowg * EE + col] = v;
      } else {
        const int h = col >> 6, d = col & 63;
        const int bh = b * HH + h;
        if (MODE == 2)
          outb[((size_t)bh * HD + d) * SS + t] = (bf16)v;   // vhT[bh][d][s]
        else
          outb[((size_t)bh * LL + t) * HD + d] = (bf16)v;   // qh/kh[bh][t][d]
      }
    }
  }
}

// ---------------------------------------------------------------------------
// Column softmax stats over L for each (bh, s). Block = 64 s-cols of one bh;
// 4 waves split L into 256-row slices; LDS merge at the end.
// XCD-grouped: all 16 blocks of a bh land on the same XCD (bh % 8 == blk % 8).
// ---------------------------------------------------------------------------
__global__ __launch_bounds__(256) void stats_kernel(
    const bf16* __restrict__ qh, const bf16* __restrict__ kh,
    float* __restrict__ ms, float* __restrict__ dinv) {
  __shared__ float sm[4][4][16], sd[4][4][16];
  const int tid = threadIdx.x;
  const int wv = tid >> 6, lane = tid & 63;
  const int lrow = lane & 15, lkg = lane >> 4;
  const int n = blockIdx.x;
  const int j = n >> 3;
  const int bh = (n & 7) + 8 * (j >> 4);
  const int s0 = (j & 15) * 64;

  bf16x8 b0[4], b1[4];
#pragma unroll
  for (int ct = 0; ct < 4; ++ct) {
    const bf16* kp = kh + ((size_t)bh * SS + s0 + ct * 16 + lrow) * HD + lkg * 8;
    b0[ct] = *reinterpret_cast<const bf16x8*>(kp);
    b1[ct] = *reinterpret_cast<const bf16x8*>(kp + 32);
  }

  const f32x4 zero = {0.f, 0.f, 0.f, 0.f};
  float m[4] = {-1e30f, -1e30f, -1e30f, -1e30f};
  float d[4] = {0.f, 0.f, 0.f, 0.f};
  const bf16* qbase = qh + ((size_t)bh * LL + wv * 256 + lrow) * HD + lkg * 8;
  for (int i = 0; i < 16; ++i) {
    bf16x8 a0 = *reinterpret_cast<const bf16x8*>(qbase + (size_t)i * 16 * HD);
    bf16x8 a1 = *reinterpret_cast<const bf16x8*>(qbase + (size_t)i * 16 * HD + 32);
#pragma unroll
    for (int ct = 0; ct < 4; ++ct) {
      f32x4 c = zero;
      c = mfma16(a0, b0[ct], c);
      c = mfma16(a1, b1[ct], c);
      float tm = fmaxf(fmaxf(c[0], c[1]), fmaxf(c[2], c[3]));
      float nm = fmaxf(m[ct], tm);
      float dd = d[ct] * __expf(m[ct] - nm);
#pragma unroll
      for (int r = 0; r < 4; ++r) dd += __expf(c[r] - nm);
      d[ct] = dd; m[ct] = nm;
    }
  }
  // combine the 4 row-groups within the wave (lanes l, l^16, l^32, l^48 share col)
#pragma unroll
  for (int off = 16; off < 64; off <<= 1) {
#pragma unroll
    for (int ct = 0; ct < 4; ++ct) {
      float mo = __shfl_xor(m[ct], off);
      float dd = __shfl_xor(d[ct], off);
      float nm = fmaxf(m[ct], mo);
      d[ct] = d[ct] * __expf(m[ct] - nm) + dd * __expf(mo - nm);
      m[ct] = nm;
    }
  }
  if (lkg == 0) {
#pragma unroll
    for (int ct = 0; ct < 4; ++ct) { sm[wv][ct][lrow] = m[ct]; sd[wv][ct][lrow] = d[ct]; }
  }
  __syncthreads();
  if (wv == 0 && lkg == 0) {
#pragma unroll
    for (int ct = 0; ct < 4; ++ct) {
      float mm = sm[0][ct][lrow], dd = sd[0][ct][lrow];
#pragma unroll
      for (int w = 1; w < 4; ++w) {
        float mo = sm[w][ct][lrow], d2 = sd[w][ct][lrow];
        float nm = fmaxf(mm, mo);
        dd = dd * __expf(mm - nm) + d2 * __expf(mo - nm);
        mm = nm;
      }
      const int s = s0 + ct * 16 + lrow;
      ms[(size_t)bh * SS + s] = mm;
      dinv[(size_t)bh * SS + s] = 1.f / dd;
    }
  }
}

// colsum_v[bh][d] = sum_s vhT[bh][d][s]   (for the +1e-8 correction)
__global__ __launch_bounds__(64) void colsum_kernel(
    const bf16* __restrict__ vhT, float* __restrict__ colsum) {
  const int bh = blockIdx.x, d = blockIdx.y, lane = threadIdx.x;
  const bf16* p = vhT + ((size_t)bh * HD + d) * SS;
  float s = 0.f;
  for (int i = lane; i < SS; i += 64) s += (float)p[i];
#pragma unroll
  for (int off = 32; off; off >>= 1) s += __shfl_xor(s, off);
  if (lane == 0) colsum[bh * HD + d] = s;
}

// vmT[bh][d][m] = v_mem[m][b][h*64+d]  (f32 -> bf16)
__global__ __launch_bounds__(256) void vmt_kernel(
    const float* __restrict__ v_mem, bf16* __restrict__ vmT) {
  const int bh = blockIdx.x;
  const int b = bh >> 4, h = bh & 15;
  const int tid = threadIdx.x;
  const int d = tid & 63;
  const int mo = tid >> 6;
  for (int m = mo; m < MM; m += 4) {
    float v = v_mem[((size_t)m * BB + b) * EE + h * 64 + d];
    vmT[((size_t)bh * HD + d) * MM + m] = (bf16)v;
  }
}

// ---------------------------------------------------------------------------
// Attention: main (col-softmax + row-renorm) + memory attention + gating.
// One wave = 32 query rows. XCD-grouped blocks (bh % 8 == blk % 8) so each
// XCD's L2 holds its 8 heads' K/V panels (2 MB). No cross-wave LDS -> no
// barriers. Recomputes scores instead of storing SxL.
// ---------------------------------------------------------------------------
__global__ __launch_bounds__(256) void attn_kernel(
    const bf16* __restrict__ qh, const bf16* __restrict__ kh,
    const bf16* __restrict__ vhT, const bf16* __restrict__ vmT,
    const bf16* __restrict__ k_mem, const float* __restrict__ gate_w,
    const float* __restrict__ ms, const float* __restrict__ dinv,
    const float* __restrict__ colsum, bf16* __restrict__ attn2) {
  __shared__ bf16 wt[4][32][40];  // per-wave P-tile, stride 40 (16B-aligned rows)
  const int tid = threadIdx.x;
  const int wv = tid >> 6, lane = tid & 63;
  const int lrow = lane & 15, lkg = lane >> 4;
  const int n = blockIdx.x;
  const int j = n >> 3;
  const int bh = (n & 7) + 8 * (j >> 3);
  const int b = bh >> 4, h = bh & 15;
  const int l0 = (j & 7) * 128 + wv * 32;

  bf16x8 aq[2][2];
#pragma unroll
  for (int rt = 0; rt < 2; ++rt) {
    const bf16* qp = qh + ((size_t)bh * LL + l0 + rt * 16 + lrow) * HD + lkg * 8;
    aq[rt][0] = *reinterpret_cast<const bf16x8*>(qp);
    aq[rt][1] = *reinterpret_cast<const bf16x8*>(qp + 32);
  }

  const f32x4 zero = {0.f, 0.f, 0.f, 0.f};
  f32x4 acc[2][4], accm[2][4];
  float rsum[2][4];
#pragma unroll
  for (int rt = 0; rt < 2; ++rt)
#pragma unroll
    for (int i = 0; i < 4; ++i) { acc[rt][i] = zero; accm[rt][i] = zero; rsum[rt][i] = 0.f; }

  // ---- main attention ----
  for (int s0 = 0; s0 < SS; s0 += 32) {
    bf16x8 k0[2], k1[2];
#pragma unroll
    for (int t = 0; t < 2; ++t) {
      const bf16* kp = kh + ((size_t)bh * SS + s0 + t * 16 + lrow) * HD + lkg * 8;
      k0[t] = *reinterpret_cast<const bf16x8*>(kp);
      k1[t] = *reinterpret_cast<const bf16x8*>(kp + 32);
    }
    f32x4 sc[2][2];
#pragma unroll
    for (int rt = 0; rt < 2; ++rt)
#pragma unroll
      for (int t = 0; t < 2; ++t) {
        f32x4 c = zero;
        c = mfma16(aq[rt][0], k0[t], c);
        c = mfma16(aq[rt][1], k1[t], c);
        sc[rt][t] = c;
      }
#pragma unroll
    for (int t = 0; t < 2; ++t) {
      const int s = s0 + t * 16 + lrow;
      const float m_ = ms[(size_t)bh * SS + s];
      const float di = dinv[(size_t)bh * SS + s];
#pragma unroll
      for (int rt = 0; rt < 2; ++rt)
#pragma unroll
        for (int r = 0; r < 4; ++r) {
          float w = __expf(sc[rt][t][r] - m_) * di;  // column-softmax value
          rsum[rt][r] += w;
          wt[wv][rt * 16 + lkg * 4 + r][t * 16 + lrow] = (bf16)w;
        }
    }
    bf16x8 aw[2];
#pragma unroll
    for (int rt = 0; rt < 2; ++rt)
      aw[rt] = *reinterpret_cast<const bf16x8*>(&wt[wv][rt * 16 + lrow][lkg * 8]);
#pragma unroll
    for (int dt = 0; dt < 4; ++dt) {
      const bf16* vp = vhT + ((size_t)bh * HD + dt * 16 + lrow) * SS + s0 + lkg * 8;
      bf16x8 bv = *reinterpret_cast<const bf16x8*>(vp);
#pragma unroll
      for (int rt = 0; rt < 2; ++rt) acc[rt][dt] = mfma16(aw[rt], bv, acc[rt][dt]);
    }
  }

  // ---- memory attention pass 1: per-row online stats ----
  float mx[2][4], dn[2][4];
#pragma unroll
  for (int rt = 0; rt < 2; ++rt)
#pragma unroll
    for (int r = 0; r < 4; ++r) { mx[rt][r] = -1e30f; dn[rt][r] = 0.f; }
  for (int m0 = 0; m0 < MM; m0 += 32) {
#pragma unroll
    for (int t = 0; t < 2; ++t) {
      const bf16* kp = k_mem + ((size_t)(m0 + t * 16 + lrow) * BB + b) * EE + h * 64 + lkg * 8;
      bf16x8 km0 = *reinterpret_cast<const bf16x8*>(kp);
      bf16x8 km1 = *reinterpret_cast<const bf16x8*>(kp + 32);
#pragma unroll
      for (int rt = 0; rt < 2; ++rt) {
        f32x4 c = zero;
        c = mfma16(aq[rt][0], km0, c);
        c = mfma16(aq[rt][1], km1, c);
#pragma unroll
        for (int r = 0; r < 4; ++r) {
          float nm = fmaxf(mx[rt][r], c[r]);
          dn[rt][r] = dn[rt][r] * __expf(mx[rt][r] - nm) + __expf(c[r] - nm);
          mx[rt][r] = nm;
        }
      }
    }
  }
#pragma unroll
  for (int off = 1; off < 16; off <<= 1) {
#pragma unroll
    for (int rt = 0; rt < 2; ++rt)
#pragma unroll
      for (int r = 0; r < 4; ++r) {
        float mo = __shfl_xor(mx[rt][r], off);
        float dd = __shfl_xor(dn[rt][r], off);
        float nm = fmaxf(mx[rt][r], mo);
        dn[rt][r] = dn[rt][r] * __expf(mx[rt][r] - nm) + dd * __expf(mo - nm);
        mx[rt][r] = nm;
      }
  }
#pragma unroll
  for (int rt = 0; rt < 2; ++rt)
#pragma unroll
    for (int r = 0; r < 4; ++r) dn[rt][r] = 1.f / dn[rt][r];

  // ---- memory attention pass 2: weights + PV ----
  for (int m0 = 0; m0 < MM; m0 += 32) {
#pragma unroll
    for (int t = 0; t < 2; ++t) {
      const bf16* kp = k_mem + ((size_t)(m0 + t * 16 + lrow) * BB + b) * EE + h * 64 + lkg * 8;
      bf16x8 km0 = *reinterpret_cast<const bf16x8*>(kp);
      bf16x8 km1 = *reinterpret_cast<const bf16x8*>(kp + 32);
#pragma unroll
      for (int rt = 0; rt < 2; ++rt) {
        f32x4 c = zero;
        c = mfma16(aq[rt][0], km0, c);
        c = mfma16(aq[rt][1], km1, c);
#pragma unroll
        for (int r = 0; r < 4; ++r) {
          float w = __expf(c[r] - mx[rt][r]) * dn[rt][r];
          wt[wv][rt * 16 + lkg * 4 + r][t * 16 + lrow] = (bf16)w;
        }
      }
    }
    bf16x8 aw[2];
#pragma unroll
    for (int rt = 0; rt < 2; ++rt)
      aw[rt] = *reinterpret_cast<const bf16x8*>(&wt[wv][rt * 16 + lrow][lkg * 8]);
#pragma unroll
    for (int dt = 0; dt < 4; ++dt) {
      const bf16* vp = vmT + ((size_t)bh * HD + dt * 16 + lrow) * MM + m0 + lkg * 8;
      bf16x8 bv = *reinterpret_cast<const bf16x8*>(vp);
#pragma unroll
      for (int rt = 0; rt < 2; ++rt) accm[rt][dt] = mfma16(aw[rt], bv, accm[rt][dt]);
    }
  }

  // ---- epilogue: renormalize, gate, store ----
#pragma unroll
  for (int off = 1; off < 16; off <<= 1) {
#pragma unroll
    for (int rt = 0; rt < 2; ++rt)
#pragma unroll
      for (int r = 0; r < 4; ++r) rsum[rt][r] += __shfl_xor(rsum[rt][r], off);
  }
  float g = gate_w[h];
  g = 1.f / (1.f + __expf(-g));

#pragma unroll
  for (int dt = 0; dt < 4; ++dt) {
    const int d = dt * 16 + lrow;
    const float cv = colsum[bh * HD + d] * 1e-8f;
#pragma unroll
    for (int rt = 0; rt < 2; ++rt)
#pragma unroll
      for (int r = 0; r < 4; ++r) {
        const int lg = l0 + rt * 16 + lkg * 4 + r;
        const float den = rsum[rt][r] + (float)SS * 1e-8f;
        const float amain = (acc[rt][dt][r] + cv) / den;
        const float v = g * accm[rt][dt][r] + (1.f - g) * amain;
        attn2[((size_t)lg * BB + b) * EE + h * 64 + d] = (bf16)v;
      }
  }
}

// ---------------------------------------------------------------------------
extern "C" void kernel_launch(void* const* d_in, const int* in_sizes, int n_in,
                              void* d_out, int out_size, void* d_ws, size_t ws_size,
                              hipStream_t stream) {
  const float* query = (const float*)d_in[0];
  const float* key_i = (const float*)d_in[1];
  const float* value = (const float*)d_in[2];
  const float* ipw   = (const float*)d_in[3];
  const float* ipb   = (const float*)d_in[4];
  const float* opw   = (const float*)d_in[5];
  const float* opb   = (const float*)d_in[6];
  const float* q_pe  = (const float*)d_in[7];
  const float* kv_pe = (const float*)d_in[8];
  const float* k_mem = (const float*)d_in[9];
  const float* v_mem = (const float*)d_in[10];
  const float* gate  = (const float*)d_in[11];

  char* ws = (char*)d_ws;
  bf16* qh    = (bf16*)(ws);                  // 8 MB  (BH, L, HD)
  bf16* kh    = (bf16*)(ws + (8u << 20));     // 8 MB  (BH, S, HD)
  bf16* vhT   = (bf16*)(ws + (16u << 20));    // 8 MB  (BH, HD, S)
  bf16* attn2 = (bf16*)(ws + (24u << 20));    // 8 MB  (L*B, E)
  bf16* vmT   = (bf16*)(ws + (32u << 20));    // 2 MB  (BH, HD, M)
  float* ms     = (float*)(ws + (34u << 20));                 // 256 KB
  float* dinv   = (float*)(ws + (34u << 20) + (1u << 18));    // 256 KB
  float* colsum = (float*)(ws + (34u << 20) + (2u << 18));    // 16 KB
  bf16* wb    = (bf16*)(ws + (35u << 20));    // 6 MB  (3E, E) bf16
  bf16* opwb  = (bf16*)(ws + (41u << 20));    // 2 MB  (E, E)  bf16
  bf16* kmemb = (bf16*)(ws + (43u << 20));    // 2 MB  (M, B, E) bf16

  dim3 blk(256);
  // pre-convert weights + k_mem to bf16
  hipLaunchKernelGGL(cvt_kernel, dim3(1536), blk, 0, stream, ipw, wb, 3 * EE * EE / 8);
  hipLaunchKernelGGL(cvt_kernel, dim3(512), blk, 0, stream, opw, opwb, EE * EE / 8);
  hipLaunchKernelGGL(cvt_kernel, dim3(512), blk, 0, stream, k_mem, kmemb, MM * BB * EE / 8);

  dim3 gP(64, 16);  // 4096 rows / 64, 1024 cols / 64
  hipLaunchKernelGGL((proj_kernel<0>), gP, blk, 0, stream, query, (const bf16*)nullptr, wb, ipb, q_pe, qh, (float*)nullptr);
  hipLaunchKernelGGL((proj_kernel<1>), gP, blk, 0, stream, key_i, (const bf16*)nullptr, wb + (size_t)EE * EE, ipb + EE, kv_pe, kh, (float*)nullptr);
  hipLaunchKernelGGL((proj_kernel<2>), gP, blk, 0, stream, value, (const bf16*)nullptr, wb + 2 * (size_t)EE * EE, ipb + 2 * EE, (const float*)nullptr, vhT, (float*)nullptr);
  hipLaunchKernelGGL(stats_kernel, dim3(1024), blk, 0, stream, qh, kh, ms, dinv);
  hipLaunchKernelGGL(colsum_kernel, dim3(64, 64), dim3(64), 0, stream, vhT, colsum);
  hipLaunchKernelGGL(vmt_kernel, dim3(64), blk, 0, stream, v_mem, vmT);
  hipLaunchKernelGGL(attn_kernel, dim3(512), blk, 0, stream, qh, kh, vhT, vmT, kmemb, gate, ms, dinv, colsum, attn2);
  hipLaunchKernelGGL((proj_kernel<3>), gP, blk, 0, stream, (const float*)nullptr, attn2, opwb, opb, (const float*)nullptr, (bf16*)nullptr, (float*)d_out);
}

// Round 4
// 318.702 us; speedup vs baseline: 2.6417x; 1.5467x over previous
//
#include <hip/hip_runtime.h>
#include <hip/hip_bf16.h>

typedef __bf16 bf16;
typedef __bf16 bf16x8 __attribute__((ext_vector_type(8)));
typedef float f32x4 __attribute__((ext_vector_type(4)));

#define LL 1024
#define SS 1024
#define BB 4
#define EE 1024
#define HH 16
#define MM 256
#define HD 64
#define BH 64

__device__ __forceinline__ f32x4 mfma16(bf16x8 a, bf16x8 b, f32x4 c) {
  return __builtin_amdgcn_mfma_f32_16x16x32_bf16(a, b, c, 0, 0, 0);
}

__device__ __forceinline__ void gload_lds16(const bf16* g, bf16* l) {
  __builtin_amdgcn_global_load_lds(
      (const __attribute__((address_space(1))) unsigned int*)(g),
      (__attribute__((address_space(3))) unsigned int*)(l), 16, 0, 0);
}

// load 8 contiguous f32 (32B-aligned) -> bf16x8 fragment
__device__ __forceinline__ bf16x8 cvt8(const float* p) {
  const f32x4 lo = *reinterpret_cast<const f32x4*>(p);
  const f32x4 hi = *reinterpret_cast<const f32x4*>(p + 4);
  bf16x8 r;
  r[0] = (bf16)lo[0]; r[1] = (bf16)lo[1]; r[2] = (bf16)lo[2]; r[3] = (bf16)lo[3];
  r[4] = (bf16)hi[0]; r[5] = (bf16)hi[1]; r[6] = (bf16)hi[2]; r[7] = (bf16)hi[3];
  return r;
}

// f32 -> bf16 elementwise (8 elements/thread)
__global__ __launch_bounds__(256) void cvt_kernel(const float* __restrict__ in,
                                                  bf16* __restrict__ out, int n8) {
  int i = blockIdx.x * 256 + threadIdx.x;
  if (i < n8) {
    bf16x8 r = cvt8(in + (size_t)i * 8);
    *reinterpret_cast<bf16x8*>(out + (size_t)i * 8) = r;
  }
}

// ---------------------------------------------------------------------------
// Tiled GEMM (m97 structure): out = X(4096xE)bf16 @ W^T(bf16) + bias.
// BM=BN=128, BK=32, 4 waves 2x2 (64x64 each), double-buffered LDS,
// global_load_lds w=16, k8-major LDS layout (conflict-free ds_read_b128).
// MODE 0: q -> *0.125, rotary(q_pe),  write qh  (BH, L, HD) bf16
// MODE 1: k -> rotary(kv_pe),         write kh  (BH, S, HD) bf16
// MODE 2: v ->                        write vhT (BH, HD, S) bf16
// MODE 3: out-proj ->                 write (L*B, E) f32 (= d_out)
// ---------------------------------------------------------------------------
template <int MODE>
__global__ __launch_bounds__(256) void gemm_kernel(
    const bf16* __restrict__ Xb, const bf16* __restrict__ W,
    const float* __restrict__ bias, const float* __restrict__ pe,
    bf16* __restrict__ outb, float* __restrict__ outf) {
  __shared__ bf16 As[2][4096];
  __shared__ bf16 Bs[2][4096];
  const int tid = threadIdx.x;
  const int wv = tid >> 6, lane = tid & 63;
  const int lrow = lane & 15, lkg = lane >> 4;
  const int wr = wv >> 1, wc = wv & 1;
  // XCD-chunked swizzle: 256 blocks, 32 per XCD; each XCD owns 4 row-panels.
  const int n = (blockIdx.x & 7) * 32 + (blockIdx.x >> 3);
  const int rowt = n >> 3, colt = n & 7;
  const int rowA0 = rowt * 128, colB0 = colt * 128;

  // staging: issue i = wv*2+t covers LDS slots [i*64 .. i*64+63], slot s holds
  // 8 elems = X[rowA0 + (s&127)][k0 + (s>>7)*8 .. +7]  (k8-major layout)
  const f32x4 zero = {0.f, 0.f, 0.f, 0.f};
  f32x4 acc[4][4];
#pragma unroll
  for (int i = 0; i < 4; ++i)
#pragma unroll
    for (int j = 0; j < 4; ++j) acc[i][j] = zero;

  auto stage = [&](int buf, int k0) {
#pragma unroll
    for (int t = 0; t < 2; ++t) {
      const int i = wv * 2 + t;
      const int slot = i * 64 + lane;
      const int srow = slot & 127, sk8 = slot >> 7;
      gload_lds16(Xb + (size_t)(rowA0 + srow) * EE + k0 + sk8 * 8, &As[buf][i * 512]);
      gload_lds16(W + (size_t)(colB0 + srow) * EE + k0 + sk8 * 8, &Bs[buf][i * 512]);
    }
  };

  stage(0, 0);
  __syncthreads();
  for (int ks = 0; ks < 32; ++ks) {
    const int buf = ks & 1;
    if (ks < 31) stage(buf ^ 1, (ks + 1) * 32);
    bf16x8 av[4], bv[4];
#pragma unroll
    for (int i = 0; i < 4; ++i) {
      av[i] = *reinterpret_cast<const bf16x8*>(&As[buf][lkg * 1024 + (wr * 64 + i * 16 + lrow) * 8]);
      bv[i] = *reinterpret_cast<const bf16x8*>(&Bs[buf][lkg * 1024 + (wc * 64 + i * 16 + lrow) * 8]);
    }
#pragma unroll
    for (int mt = 0; mt < 4; ++mt)
#pragma unroll
      for (int nt = 0; nt < 4; ++nt)
        acc[mt][nt] = mfma16(av[mt], bv[nt], acc[mt][nt]);
    __syncthreads();  // drains vmcnt (gload_lds) + lgkm before buffer swap
  }

  // ---- epilogue ----
#pragma unroll
  for (int nt = 0; nt < 4; ++nt) {
    const int col = colB0 + wc * 64 + nt * 16 + lrow;
    const float bs = bias[col];
#pragma unroll
    for (int mt = 0; mt < 4; ++mt) {
#pragma unroll
      for (int r = 0; r < 4; ++r) {
        const int rowg = rowA0 + wr * 64 + mt * 16 + lkg * 4 + r;
        const int t = rowg >> 2;   // l or s index (rows are t*B + b)
        const int b = rowg & 3;
        float v = acc[mt][nt][r] + bs;
        if (MODE == 0) v *= 0.125f;  // HD^-0.5
        if (MODE <= 1) {
          // interleaved rotary: x2[2i]=-x[2i+1], x2[2i+1]=x[2i]; out=x*cos+x2*sin
          const float* pc = pe + (((size_t)b * LL + t) * EE + col) * 2;
          const float cs = pc[0], sn = pc[1];
          const float vp = __shfl_xor(v, 1);            // partner col^1 (lane^1)
          const float x2 = (col & 1) ? vp : -vp;
          v = v * cs + x2 * sn;
        }
        if (MODE == 3) {
          outf[(size_t)rowg * EE + col] = v;
        } else {
          const int h = col >> 6, d = col & 63;
          const int bh = b * HH + h;
          if (MODE == 2)
            outb[((size_t)bh * HD + d) * SS + t] = (bf16)v;   // vhT[bh][d][s]
          else
            outb[((size_t)bh * LL + t) * HD + d] = (bf16)v;   // qh/kh[bh][t][d]
        }
      }
    }
  }
}

// ---------------------------------------------------------------------------
// Column softmax stats over L for each (bh, s). Block = 64 s-cols of one bh;
// 4 waves split L into 256-row slices; LDS merge at the end. XCD-grouped.
// ---------------------------------------------------------------------------
__global__ __launch_bounds__(256) void stats_kernel(
    const bf16* __restrict__ qh, const bf16* __restrict__ kh,
    float* __restrict__ ms, float* __restrict__ dinv) {
  __shared__ float sm[4][4][16], sd[4][4][16];
  const int tid = threadIdx.x;
  const int wv = tid >> 6, lane = tid & 63;
  const int lrow = lane & 15, lkg = lane >> 4;
  const int n = blockIdx.x;
  const int j = n >> 3;
  const int bh = (n & 7) + 8 * (j >> 4);
  const int s0 = (j & 15) * 64;

  bf16x8 b0[4], b1[4];
#pragma unroll
  for (int ct = 0; ct < 4; ++ct) {
    const bf16* kp = kh + ((size_t)bh * SS + s0 + ct * 16 + lrow) * HD + lkg * 8;
    b0[ct] = *reinterpret_cast<const bf16x8*>(kp);
    b1[ct] = *reinterpret_cast<const bf16x8*>(kp + 32);
  }

  const f32x4 zero = {0.f, 0.f, 0.f, 0.f};
  float m[4] = {-1e30f, -1e30f, -1e30f, -1e30f};
  float d[4] = {0.f, 0.f, 0.f, 0.f};
  const bf16* qbase = qh + ((size_t)bh * LL + wv * 256 + lrow) * HD + lkg * 8;
  for (int i = 0; i < 16; ++i) {
    bf16x8 a0 = *reinterpret_cast<const bf16x8*>(qbase + (size_t)i * 16 * HD);
    bf16x8 a1 = *reinterpret_cast<const bf16x8*>(qbase + (size_t)i * 16 * HD + 32);
#pragma unroll
    for (int ct = 0; ct < 4; ++ct) {
      f32x4 c = zero;
      c = mfma16(a0, b0[ct], c);
      c = mfma16(a1, b1[ct], c);
      float tm = fmaxf(fmaxf(c[0], c[1]), fmaxf(c[2], c[3]));
      float nm = fmaxf(m[ct], tm);
      float dd = d[ct] * __expf(m[ct] - nm);
#pragma unroll
      for (int r = 0; r < 4; ++r) dd += __expf(c[r] - nm);
      d[ct] = dd; m[ct] = nm;
    }
  }
#pragma unroll
  for (int off = 16; off < 64; off <<= 1) {
#pragma unroll
    for (int ct = 0; ct < 4; ++ct) {
      float mo = __shfl_xor(m[ct], off);
      float dd = __shfl_xor(d[ct], off);
      float nm = fmaxf(m[ct], mo);
      d[ct] = d[ct] * __expf(m[ct] - nm) + dd * __expf(mo - nm);
      m[ct] = nm;
    }
  }
  if (lkg == 0) {
#pragma unroll
    for (int ct = 0; ct < 4; ++ct) { sm[wv][ct][lrow] = m[ct]; sd[wv][ct][lrow] = d[ct]; }
  }
  __syncthreads();
  if (wv == 0 && lkg == 0) {
#pragma unroll
    for (int ct = 0; ct < 4; ++ct) {
      float mm = sm[0][ct][lrow], dd = sd[0][ct][lrow];
#pragma unroll
      for (int w = 1; w < 4; ++w) {
        float mo = sm[w][ct][lrow], d2 = sd[w][ct][lrow];
        float nm = fmaxf(mm, mo);
        dd = dd * __expf(mm - nm) + d2 * __expf(mo - nm);
        mm = nm;
      }
      const int s = s0 + ct * 16 + lrow;
      ms[(size_t)bh * SS + s] = mm;
      dinv[(size_t)bh * SS + s] = 1.f / dd;
    }
  }
}

// colsum_v[bh][d] = sum_s vhT[bh][d][s]   (for the +1e-8 correction)
__global__ __launch_bounds__(64) void colsum_kernel(
    const bf16* __restrict__ vhT, float* __restrict__ colsum) {
  const int bh = blockIdx.x, d = blockIdx.y, lane = threadIdx.x;
  const bf16* p = vhT + ((size_t)bh * HD + d) * SS;
  float s = 0.f;
  for (int i = lane; i < SS; i += 64) s += (float)p[i];
#pragma unroll
  for (int off = 32; off; off >>= 1) s += __shfl_xor(s, off);
  if (lane == 0) colsum[bh * HD + d] = s;
}

// vmT[bh][d][m] = v_mem[m][b][h*64+d]  (f32 -> bf16)
__global__ __launch_bounds__(256) void vmt_kernel(
    const float* __restrict__ v_mem, bf16* __restrict__ vmT) {
  const int bh = blockIdx.x;
  const int b = bh >> 4, h = bh & 15;
  const int tid = threadIdx.x;
  const int d = tid & 63;
  const int mo = tid >> 6;
  for (int m = mo; m < MM; m += 4) {
    float v = v_mem[((size_t)m * BB + b) * EE + h * 64 + d];
    vmT[((size_t)bh * HD + d) * MM + m] = (bf16)v;
  }
}

// ---------------------------------------------------------------------------
// Attention: main (col-softmax + row-renorm) + memory attention + gating.
// One wave = 32 query rows. XCD-grouped blocks. No cross-wave barriers.
// ---------------------------------------------------------------------------
__global__ __launch_bounds__(256) void attn_kernel(
    const bf16* __restrict__ qh, const bf16* __restrict__ kh,
    const bf16* __restrict__ vhT, const bf16* __restrict__ vmT,
    const bf16* __restrict__ k_mem, const float* __restrict__ gate_w,
    const float* __restrict__ ms, const float* __restrict__ dinv,
    const float* __restrict__ colsum, bf16* __restrict__ attn2) {
  __shared__ bf16 wt[4][32][40];
  const int tid = threadIdx.x;
  const int wv = tid >> 6, lane = tid & 63;
  const int lrow = lane & 15, lkg = lane >> 4;
  const int n = blockIdx.x;
  const int j = n >> 3;
  const int bh = (n & 7) + 8 * (j >> 3);
  const int b = bh >> 4, h = bh & 15;
  const int l0 = (j & 7) * 128 + wv * 32;

  bf16x8 aq[2][2];
#pragma unroll
  for (int rt = 0; rt < 2; ++rt) {
    const bf16* qp = qh + ((size_t)bh * LL + l0 + rt * 16 + lrow) * HD + lkg * 8;
    aq[rt][0] = *reinterpret_cast<const bf16x8*>(qp);
    aq[rt][1] = *reinterpret_cast<const bf16x8*>(qp + 32);
  }

  const f32x4 zero = {0.f, 0.f, 0.f, 0.f};
  f32x4 acc[2][4], accm[2][4];
  float rsum[2][4];
#pragma unroll
  for (int rt = 0; rt < 2; ++rt)
#pragma unroll
    for (int i = 0; i < 4; ++i) { acc[rt][i] = zero; accm[rt][i] = zero; rsum[rt][i] = 0.f; }

  // ---- main attention ----
  for (int s0 = 0; s0 < SS; s0 += 32) {
    bf16x8 k0[2], k1[2];
#pragma unroll
    for (int t = 0; t < 2; ++t) {
      const bf16* kp = kh + ((size_t)bh * SS + s0 + t * 16 + lrow) * HD + lkg * 8;
      k0[t] = *reinterpret_cast<const bf16x8*>(kp);
      k1[t] = *reinterpret_cast<const bf16x8*>(kp + 32);
    }
    f32x4 sc[2][2];
#pragma unroll
    for (int rt = 0; rt < 2; ++rt)
#pragma unroll
      for (int t = 0; t < 2; ++t) {
        f32x4 c = zero;
        c = mfma16(aq[rt][0], k0[t], c);
        c = mfma16(aq[rt][1], k1[t], c);
        sc[rt][t] = c;
      }
#pragma unroll
    for (int t = 0; t < 2; ++t) {
      const int s = s0 + t * 16 + lrow;
      const float m_ = ms[(size_t)bh * SS + s];
      const float di = dinv[(size_t)bh * SS + s];
#pragma unroll
      for (int rt = 0; rt < 2; ++rt)
#pragma unroll
        for (int r = 0; r < 4; ++r) {
          float w = __expf(sc[rt][t][r] - m_) * di;
          rsum[rt][r] += w;
          wt[wv][rt * 16 + lkg * 4 + r][t * 16 + lrow] = (bf16)w;
        }
    }
    bf16x8 aw[2];
#pragma unroll
    for (int rt = 0; rt < 2; ++rt)
      aw[rt] = *reinterpret_cast<const bf16x8*>(&wt[wv][rt * 16 + lrow][lkg * 8]);
#pragma unroll
    for (int dt = 0; dt < 4; ++dt) {
      const bf16* vp = vhT + ((size_t)bh * HD + dt * 16 + lrow) * SS + s0 + lkg * 8;
      bf16x8 bv = *reinterpret_cast<const bf16x8*>(vp);
#pragma unroll
      for (int rt = 0; rt < 2; ++rt) acc[rt][dt] = mfma16(aw[rt], bv, acc[rt][dt]);
    }
  }

  // ---- memory attention pass 1: per-row online stats ----
  float mx[2][4], dn[2][4];
#pragma unroll
  for (int rt = 0; rt < 2; ++rt)
#pragma unroll
    for (int r = 0; r < 4; ++r) { mx[rt][r] = -1e30f; dn[rt][r] = 0.f; }
  for (int m0 = 0; m0 < MM; m0 += 32) {
#pragma unroll
    for (int t = 0; t < 2; ++t) {
      const bf16* kp = k_mem + ((size_t)(m0 + t * 16 + lrow) * BB + b) * EE + h * 64 + lkg * 8;
      bf16x8 km0 = *reinterpret_cast<const bf16x8*>(kp);
      bf16x8 km1 = *reinterpret_cast<const bf16x8*>(kp + 32);
#pragma unroll
      for (int rt = 0; rt < 2; ++rt) {
        f32x4 c = zero;
        c = mfma16(aq[rt][0], km0, c);
        c = mfma16(aq[rt][1], km1, c);
#pragma unroll
        for (int r = 0; r < 4; ++r) {
          float nm = fmaxf(mx[rt][r], c[r]);
          dn[rt][r] = dn[rt][r] * __expf(mx[rt][r] - nm) + __expf(c[r] - nm);
          mx[rt][r] = nm;
        }
      }
    }
  }
#pragma unroll
  for (int off = 1; off < 16; off <<= 1) {
#pragma unroll
    for (int rt = 0; rt < 2; ++rt)
#pragma unroll
      for (int r = 0; r < 4; ++r) {
        float mo = __shfl_xor(mx[rt][r], off);
        float dd = __shfl_xor(dn[rt][r], off);
        float nm = fmaxf(mx[rt][r], mo);
        dn[rt][r] = dn[rt][r] * __expf(mx[rt][r] - nm) + dd * __expf(mo - nm);
        mx[rt][r] = nm;
      }
  }
#pragma unroll
  for (int rt = 0; rt < 2; ++rt)
#pragma unroll
    for (int r = 0; r < 4; ++r) dn[rt][r] = 1.f / dn[rt][r];

  // ---- memory attention pass 2: weights + PV ----
  for (int m0 = 0; m0 < MM; m0 += 32) {
#pragma unroll
    for (int t = 0; t < 2; ++t) {
      const bf16* kp = k_mem + ((size_t)(m0 + t * 16 + lrow) * BB + b) * EE + h * 64 + lkg * 8;
      bf16x8 km0 = *reinterpret_cast<const bf16x8*>(kp);
      bf16x8 km1 = *reinterpret_cast<const bf16x8*>(kp + 32);
#pragma unroll
      for (int rt = 0; rt < 2; ++rt) {
        f32x4 c = zero;
        c = mfma16(aq[rt][0], km0, c);
        c = mfma16(aq[rt][1], km1, c);
#pragma unroll
        for (int r = 0; r < 4; ++r) {
          float w = __expf(c[r] - mx[rt][r]) * dn[rt][r];
          wt[wv][rt * 16 + lkg * 4 + r][t * 16 + lrow] = (bf16)w;
        }
      }
    }
    bf16x8 aw[2];
#pragma unroll
    for (int rt = 0; rt < 2; ++rt)
      aw[rt] = *reinterpret_cast<const bf16x8*>(&wt[wv][rt * 16 + lrow][lkg * 8]);
#pragma unroll
    for (int dt = 0; dt < 4; ++dt) {
      const bf16* vp = vmT + ((size_t)bh * HD + dt * 16 + lrow) * MM + m0 + lkg * 8;
      bf16x8 bv = *reinterpret_cast<const bf16x8*>(vp);
#pragma unroll
      for (int rt = 0; rt < 2; ++rt) accm[rt][dt] = mfma16(aw[rt], bv, accm[rt][dt]);
    }
  }

  // ---- epilogue ----
#pragma unroll
  for (int off = 1; off < 16; off <<= 1) {
#pragma unroll
    for (int rt = 0; rt < 2; ++rt)
#pragma unroll
      for (int r = 0; r < 4; ++r) rsum[rt][r] += __shfl_xor(rsum[rt][r], off);
  }
  float g = gate_w[h];
  g = 1.f / (1.f + __expf(-g));

#pragma unroll
  for (int dt = 0; dt < 4; ++dt) {
    const int d = dt * 16 + lrow;
    const float cv = colsum[bh * HD + d] * 1e-8f;
#pragma unroll
    for (int rt = 0; rt < 2; ++rt)
#pragma unroll
      for (int r = 0; r < 4; ++r) {
        const int lg = l0 + rt * 16 + lkg * 4 + r;
        const float den = rsum[rt][r] + (float)SS * 1e-8f;
        const float amain = (acc[rt][dt][r] + cv) / den;
        const float v = g * accm[rt][dt][r] + (1.f - g) * amain;
        attn2[((size_t)lg * BB + b) * EE + h * 64 + d] = (bf16)v;
      }
  }
}

// ---------------------------------------------------------------------------
extern "C" void kernel_launch(void* const* d_in, const int* in_sizes, int n_in,
                              void* d_out, int out_size, void* d_ws, size_t ws_size,
                              hipStream_t stream) {
  const float* query = (const float*)d_in[0];
  const float* key_i = (const float*)d_in[1];
  const float* value = (const float*)d_in[2];
  const float* ipw   = (const float*)d_in[3];
  const float* ipb   = (const float*)d_in[4];
  const float* opw   = (const float*)d_in[5];
  const float* opb   = (const float*)d_in[6];
  const float* q_pe  = (const float*)d_in[7];
  const float* kv_pe = (const float*)d_in[8];
  const float* k_mem = (const float*)d_in[9];
  const float* v_mem = (const float*)d_in[10];
  const float* gate  = (const float*)d_in[11];

  char* ws = (char*)d_ws;
  bf16* qh    = (bf16*)(ws);                  // 8 MB  (BH, L, HD)
  bf16* kh    = (bf16*)(ws + (8u << 20));     // 8 MB  (BH, S, HD)
  bf16* vhT   = (bf16*)(ws + (16u << 20));    // 8 MB  (BH, HD, S)
  bf16* attn2 = (bf16*)(ws + (24u << 20));    // 8 MB  (L*B, E); also bf16-X scratch pre-attn
  bf16* vmT   = (bf16*)(ws + (32u << 20));    // 2 MB  (BH, HD, M)
  float* ms     = (float*)(ws + (34u << 20));                 // 256 KB
  float* dinv   = (float*)(ws + (34u << 20) + (1u << 18));    // 256 KB
  float* colsum = (float*)(ws + (34u << 20) + (2u << 18));    // 16 KB
  bf16* wb    = (bf16*)(ws + (35u << 20));    // 6 MB  (3E, E) bf16
  bf16* opwb  = (bf16*)(ws + (41u << 20));    // 2 MB  (E, E)  bf16
  bf16* kmemb = (bf16*)(ws + (43u << 20));    // 2 MB  (M, B, E) bf16
  bf16* xs = attn2;  // 8 MB bf16 input scratch (sequential reuse; attn2 written later)

  dim3 blk(256);
  dim3 gG(256);  // 32 row-tiles x 8 col-tiles
  // weights + k_mem to bf16
  hipLaunchKernelGGL(cvt_kernel, dim3(1536), blk, 0, stream, ipw, wb, 3 * EE * EE / 8);
  hipLaunchKernelGGL(cvt_kernel, dim3(512), blk, 0, stream, opw, opwb, EE * EE / 8);
  hipLaunchKernelGGL(cvt_kernel, dim3(512), blk, 0, stream, k_mem, kmemb, MM * BB * EE / 8);

  hipLaunchKernelGGL(cvt_kernel, dim3(2048), blk, 0, stream, query, xs, LL * BB * EE / 8);
  hipLaunchKernelGGL((gemm_kernel<0>), gG, blk, 0, stream, xs, wb, ipb, q_pe, qh, (float*)nullptr);
  hipLaunchKernelGGL(cvt_kernel, dim3(2048), blk, 0, stream, key_i, xs, SS * BB * EE / 8);
  hipLaunchKernelGGL((gemm_kernel<1>), gG, blk, 0, stream, xs, wb + (size_t)EE * EE, ipb + EE, kv_pe, kh, (float*)nullptr);
  hipLaunchKernelGGL(cvt_kernel, dim3(2048), blk, 0, stream, value, xs, SS * BB * EE / 8);
  hipLaunchKernelGGL((gemm_kernel<2>), gG, blk, 0, stream, xs, wb + 2 * (size_t)EE * EE, ipb + 2 * EE, (const float*)nullptr, vhT, (float*)nullptr);

  hipLaunchKernelGGL(stats_kernel, dim3(1024), blk, 0, stream, qh, kh, ms, dinv);
  hipLaunchKernelGGL(colsum_kernel, dim3(64, 64), dim3(64), 0, stream, vhT, colsum);
  hipLaunchKernelGGL(vmt_kernel, dim3(64), blk, 0, stream, v_mem, vmT);
  hipLaunchKernelGGL(attn_kernel, dim3(512), blk, 0, stream, qh, kh, vhT, vmT, kmemb, gate, ms, dinv, colsum, attn2);
  hipLaunchKernelGGL((gemm_kernel<3>), gG, blk, 0, stream, attn2, opwb, opb, (const float*)nullptr, (bf16*)nullptr, (float*)d_out);
}